// Round 1
// baseline (17.331 us; speedup 1.0000x reference)
//
#include <hip/hip_runtime.h>
#include <hip/hip_bf16.h>

// Reference analysis: softmax over a singleton axis (axis=1 of [B,1,H,W])
// is identically 1.0 for finite inputs. The entire output [8, 81, 96, 128]
// float32 is the constant 1.0f. This kernel is a vectorized constant fill.

__global__ void fill_ones_f4(float4* __restrict__ out, int n4) {
    int i = blockIdx.x * blockDim.x + threadIdx.x;
    if (i < n4) {
        out[i] = make_float4(1.0f, 1.0f, 1.0f, 1.0f);
    }
}

__global__ void fill_ones_tail(float* __restrict__ out, int start, int n) {
    int i = start + blockIdx.x * blockDim.x + threadIdx.x;
    if (i < n) {
        out[i] = 1.0f;
    }
}

extern "C" void kernel_launch(void* const* d_in, const int* in_sizes, int n_in,
                              void* d_out, int out_size, void* d_ws, size_t ws_size,
                              hipStream_t stream) {
    (void)d_in; (void)in_sizes; (void)n_in; (void)d_ws; (void)ws_size;

    float* out = (float*)d_out;
    int n4 = out_size / 4;          // out_size = 8*81*96*128 = 7962624, divisible by 4
    int tail_start = n4 * 4;

    if (n4 > 0) {
        int block = 256;
        int grid = (n4 + block - 1) / block;
        fill_ones_f4<<<grid, block, 0, stream>>>((float4*)out, n4);
    }
    int tail = out_size - tail_start;
    if (tail > 0) {
        fill_ones_tail<<<1, 64, 0, stream>>>(out, tail_start, out_size);
    }
}

// Round 3
// 11.489 us; speedup vs baseline: 1.5084x; 1.5084x over previous
//
#include <hip/hip_runtime.h>
#include <hip/hip_bf16.h>

// Reference analysis: softmax over a singleton axis (axis=1 of [B,1,H,W])
// is identically 1.0 for finite inputs. The entire output [8, 81, 96, 128]
// float32 is the constant 1.0f. This kernel is a vectorized constant fill.
//
// R2: __builtin_nontemporal_store needs a NATIVE clang vector type, not
// HIP_vector_type<float,4>. Use ext_vector_type(4).

typedef float f32x4 __attribute__((ext_vector_type(4)));

__global__ __launch_bounds__(256) void fill_ones_f4(f32x4* __restrict__ out, int n4) {
    const f32x4 ones = {1.0f, 1.0f, 1.0f, 1.0f};
    int stride = gridDim.x * blockDim.x;
    for (int i = blockIdx.x * blockDim.x + threadIdx.x; i < n4; i += stride) {
        __builtin_nontemporal_store(ones, &out[i]);
    }
}

extern "C" void kernel_launch(void* const* d_in, const int* in_sizes, int n_in,
                              void* d_out, int out_size, void* d_ws, size_t ws_size,
                              hipStream_t stream) {
    (void)d_in; (void)in_sizes; (void)n_in; (void)d_ws; (void)ws_size;

    float* out = (float*)d_out;
    int n4 = out_size / 4;          // out_size = 8*81*96*128 = 7962624, divisible by 4
    // (out_size % 4 == 0 for this problem; no tail needed)

    int block = 256;
    int grid = (n4 + block - 1) / block;
    if (grid > 2048) grid = 2048;   // grid-stride: ~4 float4 stores per thread
    fill_ones_f4<<<grid, block, 0, stream>>>((f32x4*)out, n4);
}